// Round 5
// baseline (712.687 us; speedup 1.0000x reference)
//
#include <hip/hip_runtime.h>
#include <stdint.h>

typedef __bf16 bf16_t;
typedef __attribute__((ext_vector_type(8))) __bf16 bf16x8;
typedef __attribute__((ext_vector_type(4))) float f32x4;

#define NDIM 4096

// ---------------------------------------------------------------------------
// BFP quantize: groups of 64 along last dim share exponent of group max.
// 8 floats / thread -> group of 64 = 8 lanes -> butterfly max over 8 lanes.
// Output exactly-representable-in-bf16 values q * 2^(e-7), q in [-128,127].
// ---------------------------------------------------------------------------
__global__ __launch_bounds__(256) void quant_bfp(const float* __restrict__ in0,
                                                 bf16_t* __restrict__ out0,
                                                 const float* __restrict__ in1,
                                                 bf16_t* __restrict__ out1) {
    const float* in = blockIdx.y ? in1 : in0;
    bf16_t* out     = blockIdx.y ? out1 : out0;
    const int t = blockIdx.x * 256 + threadIdx.x;
    float4 a = ((const float4*)in)[2 * t];
    float4 b = ((const float4*)in)[2 * t + 1];
    float m = fmaxf(fmaxf(fmaxf(fabsf(a.x), fabsf(a.y)), fmaxf(fabsf(a.z), fabsf(a.w))),
                    fmaxf(fmaxf(fabsf(b.x), fabsf(b.y)), fmaxf(fabsf(b.z), fabsf(b.w))));
    m = fmaxf(m, __shfl_xor(m, 1));
    m = fmaxf(m, __shfl_xor(m, 2));
    m = fmaxf(m, __shfl_xor(m, 4));
    const int e = (int)((__float_as_uint(m) >> 23) & 0xFF) - 127;
    float step = __uint_as_float((uint32_t)(e + 120) << 23);  // 2^(e-7)
    float inv  = __uint_as_float((uint32_t)(134 - e) << 23);  // 2^(7-e)
    if (m == 0.0f) { step = 0.0f; inv = 0.0f; }
    float q[8] = {a.x, a.y, a.z, a.w, b.x, b.y, b.z, b.w};
    union { bf16_t h[8]; uint4 u; } o;
#pragma unroll
    for (int i = 0; i < 8; ++i)
        o.h[i] = (bf16_t)(fminf(fmaxf(rintf(q[i] * inv), -128.0f), 127.0f) * step);
    ((uint4*)out)[t] = o.u;
}

// ---------------------------------------------------------------------------
// 128x128 tile, BK=64, 16x16x32 bf16 MFMA.
// VGPR-staged prefetch pipeline: buffer_load tile k+1 into registers right
// after the post-ds_write barrier, compute 32 MFMAs (hides load latency),
// then the next barrier's vmcnt(0) drain is cheap. LDS stays 32 KB
// single-buffered (occupancy preserved, unlike LDS double-buffer).
// XOR-swizzled LDS (slot (row,c) holds global chunk c^(row&7)) -> 0 conflicts.
// ---------------------------------------------------------------------------
__global__ __launch_bounds__(256) void gemm_bfp(const bf16_t* __restrict__ A,
                                                const bf16_t* __restrict__ B,
                                                const float* __restrict__ bias,
                                                float* __restrict__ C) {
    __shared__ bf16_t sA[128 * 64];
    __shared__ bf16_t sB[128 * 64];

    const int tid  = threadIdx.x;
    const int wave = tid >> 6;
    const int lane = tid & 63;

    // XCD-pinning remap: XCD x (= p%8) always works on bn in [4x, 4x+4)
    const int p  = blockIdx.y * 32 + blockIdx.x;
    const int bn = ((p & 7) << 2) | ((p >> 3) & 3);
    const int bm = p >> 5;

    const int m_wave = (wave >> 1) * 64;
    const int n_wave = (wave & 1) * 64;

    // staging: thread tid owns LDS slot (row = tid>>3, chunk = tid&7);
    // global source chunk is (tid&7) ^ (row&7)  [xor swizzle]
    const int srow = tid >> 3;                                  // 0..31
    const int swz  = (((tid & 7) ^ (srow & 7)) * 8);            // element offset

    const uint4* pA[4];
    const uint4* pB[4];
#pragma unroll
    for (int i = 0; i < 4; ++i) {
        pA[i] = (const uint4*)(A + (size_t)(bm * 128 + i * 32 + srow) * NDIM + swz);
        pB[i] = (const uint4*)(B + (size_t)(bn * 128 + i * 32 + srow) * NDIM + swz);
    }
    // pointer stride per BK=64 tile: 64 bf16 = 128 B = 8 uint4
    uint4* wA = (uint4*)((char*)sA + tid * 16);
    uint4* wB = (uint4*)((char*)sB + tid * 16);

    f32x4 acc[4][4];
#pragma unroll
    for (int i = 0; i < 4; ++i)
#pragma unroll
        for (int j = 0; j < 4; ++j)
            acc[i][j] = (f32x4){0.0f, 0.0f, 0.0f, 0.0f};

    const int quad = lane >> 4;
    const int l16  = lane & 15;
    const int rsw  = l16 & 7;
    const int ce0  = (quad ^ rsw) * 8;        // ks = 0 fragment offset
    const int ce1  = ((4 + quad) ^ rsw) * 8;  // ks = 32 fragment offset

    // prologue: prefetch tile 0 into registers
    uint4 rA[4], rB[4];
#pragma unroll
    for (int i = 0; i < 4; ++i) { rA[i] = *pA[i]; pA[i] += 8; }
#pragma unroll
    for (int i = 0; i < 4; ++i) { rB[i] = *pB[i]; pB[i] += 8; }

    for (int kt = 0; kt < NDIM; kt += 64) {
        if (kt) __syncthreads();   // B1: prev compute done; prev loads drained (hidden)
#pragma unroll
        for (int i = 0; i < 4; ++i) wA[i * 256] = rA[i];   // 256 uint4 = 4096 B slab
#pragma unroll
        for (int i = 0; i < 4; ++i) wB[i * 256] = rB[i];
        __syncthreads();           // B2: tile visible to all waves

        if (kt + 64 < NDIM) {      // issue next-tile loads; land during compute
#pragma unroll
            for (int i = 0; i < 4; ++i) { rA[i] = *pA[i]; pA[i] += 8; }
#pragma unroll
            for (int i = 0; i < 4; ++i) { rB[i] = *pB[i]; pB[i] += 8; }
        }

#pragma unroll
        for (int ks = 0; ks < 64; ks += 32) {
            const int ce = ks ? ce1 : ce0;
            bf16x8 af[4], bfr[4];
#pragma unroll
            for (int i = 0; i < 4; ++i)
                af[i] = *(const bf16x8*)&sA[(m_wave + i * 16 + l16) * 64 + ce];
#pragma unroll
            for (int j = 0; j < 4; ++j)
                bfr[j] = *(const bf16x8*)&sB[(n_wave + j * 16 + l16) * 64 + ce];
#pragma unroll
            for (int i = 0; i < 4; ++i)
#pragma unroll
                for (int j = 0; j < 4; ++j)
                    acc[i][j] = __builtin_amdgcn_mfma_f32_16x16x32_bf16(
                        af[i], bfr[j], acc[i][j], 0, 0, 0);
        }
    }

    // epilogue: C/D layout col = lane&15, row = quad*4 + reg  [m89-verified]
    const int row0 = bm * 128 + m_wave + quad * 4;
    const int col0 = bn * 128 + n_wave + l16;
#pragma unroll
    for (int j = 0; j < 4; ++j) {
        const int c = col0 + j * 16;
        const float bv = 2.0f * bias[c];
#pragma unroll
        for (int i = 0; i < 4; ++i) {
            const int r = row0 + i * 16;
#pragma unroll
            for (int reg = 0; reg < 4; ++reg)
                C[(size_t)(r + reg) * NDIM + c] = acc[i][j][reg] + bv;
        }
    }
}

extern "C" void kernel_launch(void* const* d_in, const int* in_sizes, int n_in,
                              void* d_out, int out_size, void* d_ws, size_t ws_size,
                              hipStream_t stream) {
    const float* x    = (const float*)d_in[0];
    const float* w    = (const float*)d_in[1];
    const float* bias = (const float*)d_in[2];
    float* out = (float*)d_out;

    bf16_t* xq = (bf16_t*)d_ws;                         // 32 MB
    bf16_t* wq = xq + (size_t)NDIM * NDIM;              // 32 MB

    const int qblocks = (NDIM * NDIM / 8) / 256;        // 8192
    dim3 qgrid(qblocks, 2);
    quant_bfp<<<qgrid, 256, 0, stream>>>(x, xq, w, wq);

    dim3 grid(NDIM / 128, NDIM / 128);                  // 32 x 32
    gemm_bfp<<<grid, 256, 0, stream>>>(xq, wq, bias, out);
}

// Round 6
// 293.199 us; speedup vs baseline: 2.4307x; 2.4307x over previous
//
#include <hip/hip_runtime.h>
#include <stdint.h>

typedef __bf16 bf16_t;
typedef __attribute__((ext_vector_type(8))) __bf16 bf16x8;
typedef __attribute__((ext_vector_type(4))) float f32x4;

#define NDIM 4096

// ---------------------------------------------------------------------------
// BFP quantize: groups of 64 along last dim share exponent of group max.
// 4 floats / thread -> group of 64 = 16 lanes -> butterfly max over 16 lanes.
// Output exactly-representable-in-bf16 values q * 2^(e-7), q in [-128,127].
// grid.y selects tensor (0 = x, 1 = w).
// ---------------------------------------------------------------------------
__global__ __launch_bounds__(256) void quant_bfp(const float* __restrict__ in0,
                                                 bf16_t* __restrict__ out0,
                                                 const float* __restrict__ in1,
                                                 bf16_t* __restrict__ out1) {
    const float* in = blockIdx.y ? in1 : in0;
    bf16_t* out     = blockIdx.y ? out1 : out0;
    const int t = blockIdx.x * 256 + threadIdx.x;
    float4 v = ((const float4*)in)[t];
    float m = fmaxf(fmaxf(fabsf(v.x), fabsf(v.y)), fmaxf(fabsf(v.z), fabsf(v.w)));
    m = fmaxf(m, __shfl_xor(m, 1));
    m = fmaxf(m, __shfl_xor(m, 2));
    m = fmaxf(m, __shfl_xor(m, 4));
    m = fmaxf(m, __shfl_xor(m, 8));
    const int e = (int)((__float_as_uint(m) >> 23) & 0xFF) - 127;
    float step = __uint_as_float((uint32_t)(e + 120) << 23);  // 2^(e-7)
    float inv  = __uint_as_float((uint32_t)(134 - e) << 23);  // 2^(7-e)
    if (m == 0.0f) { step = 0.0f; inv = 0.0f; }                // maxabs==0 -> 0
    float q0 = fminf(fmaxf(rintf(v.x * inv), -128.0f), 127.0f) * step;
    float q1 = fminf(fmaxf(rintf(v.y * inv), -128.0f), 127.0f) * step;
    float q2 = fminf(fmaxf(rintf(v.z * inv), -128.0f), 127.0f) * step;
    float q3 = fminf(fmaxf(rintf(v.w * inv), -128.0f), 127.0f) * step;
    union { bf16_t b[4]; uint2 u; } o;
    o.b[0] = (bf16_t)q0; o.b[1] = (bf16_t)q1;
    o.b[2] = (bf16_t)q2; o.b[3] = (bf16_t)q3;
    ((uint2*)out)[t] = o.u;
}

// ---------------------------------------------------------------------------
// R4 GEMM (proven 903 TF): 128x128 tile, BK=64, 16x16x32 bf16 MFMA,
// global_load_lds width-16 staging, XOR-swizzled LDS (0 bank conflicts),
// XCD-pinned block remap, persistent staging pointers.
// ---------------------------------------------------------------------------
__device__ __forceinline__ void g2l16(const bf16_t* g, void* l) {
    __builtin_amdgcn_global_load_lds(
        (__attribute__((address_space(1))) void*)g,
        (__attribute__((address_space(3))) void*)l, 16, 0, 0);
}

__global__ __launch_bounds__(256) void gemm_bfp(const bf16_t* __restrict__ A,
                                                const bf16_t* __restrict__ B,
                                                const float* __restrict__ bias,
                                                float* __restrict__ C) {
    __shared__ bf16_t sA[128 * 64];
    __shared__ bf16_t sB[128 * 64];

    const int tid  = threadIdx.x;
    const int wave = tid >> 6;
    const int lane = tid & 63;

    // XCD-pinning remap: XCD x (= p%8) always works on bn in [4x, 4x+4)
    const int p  = blockIdx.y * 32 + blockIdx.x;
    const int bn = ((p & 7) << 2) | ((p >> 3) & 3);
    const int bm = p >> 5;

    const int m_wave = (wave >> 1) * 64;
    const int n_wave = (wave & 1) * 64;

    // staging: thread tid writes LDS slot (row = tid>>3, chunk = tid&7);
    // source chunk is (tid&7) ^ (row&7)  [xor swizzle]
    const int srow = tid >> 3;                                  // 0..31
    const int swz  = (((tid & 7) ^ (srow & 7)) * 8);            // element offset

    // persistent per-slab global pointers, advanced by BK each iteration
    const bf16_t* pA[4];
    const bf16_t* pB[4];
#pragma unroll
    for (int i = 0; i < 4; ++i) {
        pA[i] = A + (size_t)(bm * 128 + i * 32 + srow) * NDIM + swz;
        pB[i] = B + (size_t)(bn * 128 + i * 32 + srow) * NDIM + swz;
    }

    f32x4 acc[4][4];
#pragma unroll
    for (int i = 0; i < 4; ++i)
#pragma unroll
        for (int j = 0; j < 4; ++j)
            acc[i][j] = (f32x4){0.0f, 0.0f, 0.0f, 0.0f};

    const int quad = lane >> 4;   // 0..3
    const int l16  = lane & 15;
    const int rsw  = l16 & 7;     // read-side swizzle key (row & 7 == l16 & 7)
    const int ce0  = (quad ^ rsw) * 8;        // ks = 0 fragment chunk offset
    const int ce1  = ((4 + quad) ^ rsw) * 8;  // ks = 32 fragment chunk offset

    for (int kt = 0; kt < NDIM; kt += 64) {
#pragma unroll
        for (int i = 0; i < 4; ++i) {
            g2l16(pA[i], (char*)sA + i * 4096 + tid * 16);
            pA[i] += 64;
        }
#pragma unroll
        for (int i = 0; i < 4; ++i) {
            g2l16(pB[i], (char*)sB + i * 4096 + tid * 16);
            pB[i] += 64;
        }
        __syncthreads();

#pragma unroll
        for (int ks = 0; ks < 64; ks += 32) {
            const int ce = ks ? ce1 : ce0;
            bf16x8 af[4], bfr[4];
#pragma unroll
            for (int i = 0; i < 4; ++i)
                af[i] = *(const bf16x8*)&sA[(m_wave + i * 16 + l16) * 64 + ce];
#pragma unroll
            for (int j = 0; j < 4; ++j)
                bfr[j] = *(const bf16x8*)&sB[(n_wave + j * 16 + l16) * 64 + ce];
#pragma unroll
            for (int i = 0; i < 4; ++i)
#pragma unroll
                for (int j = 0; j < 4; ++j)
                    acc[i][j] = __builtin_amdgcn_mfma_f32_16x16x32_bf16(
                        af[i], bfr[j], acc[i][j], 0, 0, 0);
        }
        __syncthreads();
    }

    // epilogue: C/D layout col = lane&15, row = quad*4 + reg  [m89-verified]
    const int row0 = bm * 128 + m_wave + quad * 4;
    const int col0 = bn * 128 + n_wave + l16;
#pragma unroll
    for (int j = 0; j < 4; ++j) {
        const int c = col0 + j * 16;
        const float bv = 2.0f * bias[c];
#pragma unroll
        for (int i = 0; i < 4; ++i) {
            const int r = row0 + i * 16;
#pragma unroll
            for (int reg = 0; reg < 4; ++reg)
                C[(size_t)(r + reg) * NDIM + c] = acc[i][j][reg] + bv;
        }
    }
}

extern "C" void kernel_launch(void* const* d_in, const int* in_sizes, int n_in,
                              void* d_out, int out_size, void* d_ws, size_t ws_size,
                              hipStream_t stream) {
    const float* x    = (const float*)d_in[0];
    const float* w    = (const float*)d_in[1];
    const float* bias = (const float*)d_in[2];
    float* out = (float*)d_out;

    bf16_t* xq = (bf16_t*)d_ws;                         // 32 MB
    bf16_t* wq = xq + (size_t)NDIM * NDIM;              // 32 MB

    const int qblocks = (NDIM * NDIM / 4) / 256;        // 16384
    dim3 qgrid(qblocks, 2);
    quant_bfp<<<qgrid, 256, 0, stream>>>(x, xq, w, wq);

    dim3 grid(NDIM / 128, NDIM / 128);                  // 32 x 32
    gemm_bfp<<<grid, 256, 0, stream>>>(xq, wq, bias, out);
}